// Round 1
// baseline (1265.403 us; speedup 1.0000x reference)
//
#include <hip/hip_runtime.h>

// CoreRNNFW: fused fast-weight RNN forward.
//   base = h_prev @ W_h^T + z @ W_g^T + b_h              (B, DH)
//   h = relu(LN(base))
//   3x: h = relu(LN(base + A[b] @ h))
//   A_k = 0.95*A + 0.5*outer(h,h)
// Outputs concatenated: h_t (B*DH floats) then A_k (B*DH*DH floats).
//
// Round 0 baseline: one block per batch (128 blocks x 1024 threads).
// Wave-per-row matvec with lane-strided float4 global reads (coalesced),
// shuffle-reduce over 64 lanes. LN via block reduction in LDS.

#define NB 128
#define DG 512
#define DH 1024
#define S_STEPS 3
#define LAMBDA 0.95f
#define ETA 0.5f
#define LN_EPS 1e-5f

__global__ __launch_bounds__(1024) void corernn_fused(
    const float* __restrict__ z,
    const float* __restrict__ h_prev,
    const float* __restrict__ A_prev,
    const float* __restrict__ W_h,
    const float* __restrict__ W_g,
    const float* __restrict__ bh,
    const float* __restrict__ gamma,
    const float* __restrict__ beta,
    float* __restrict__ out)
{
    __shared__ __align__(16) float s_h[DH];
    __shared__ __align__(16) float s_base[DH];
    __shared__ __align__(16) float s_add[DH];
    __shared__ __align__(16) float s_hprev[DH];
    __shared__ __align__(16) float s_z[DG];
    __shared__ float s_red[40];

    const int tid  = threadIdx.x;
    const int lane = tid & 63;
    const int wave = tid >> 6;
    const int bb   = blockIdx.x;

    // stage per-batch vectors
    s_hprev[tid] = h_prev[(size_t)bb * DH + tid];
    if (tid < DG) s_z[tid] = z[(size_t)bb * DG + tid];
    const float g  = gamma[tid];
    const float bt = beta[tid];
    __syncthreads();

    // ---- base = W_h[i,:]·h_prev + W_g[i,:]·z + b_h[i], wave-per-row ----
    for (int r = 0; r < 64; ++r) {
        const int i = wave * 64 + r;
        const float* wr = W_h + (size_t)i * DH;
        float acc = 0.f;
        #pragma unroll
        for (int k = 0; k < 4; ++k) {
            float4 wv = *(const float4*)(wr + k * 256 + 4 * lane);
            float4 hv = *(const float4*)(s_hprev + k * 256 + 4 * lane);
            acc += wv.x * hv.x + wv.y * hv.y + wv.z * hv.z + wv.w * hv.w;
        }
        const float* gr = W_g + (size_t)i * DG;
        #pragma unroll
        for (int k = 0; k < 2; ++k) {
            float4 wv = *(const float4*)(gr + k * 256 + 4 * lane);
            float4 zv = *(const float4*)(s_z + k * 256 + 4 * lane);
            acc += wv.x * zv.x + wv.y * zv.y + wv.z * zv.z + wv.w * zv.w;
        }
        #pragma unroll
        for (int o = 32; o > 0; o >>= 1) acc += __shfl_down(acc, o, 64);
        if (lane == 0) s_base[i] = acc + bh[i];
    }
    __syncthreads();

    const float* Ab = A_prev + ((size_t)bb << 20);  // A[b], 1024x1024

    // ---- step 0: relu(LN(base)); steps 1..3: relu(LN(base + A·h)) ----
    for (int step = 0; step <= S_STEPS; ++step) {
        float x;
        if (step == 0) {
            x = s_base[tid];
        } else {
            // matvec: wave-per-row, coalesced float4 reads of A row
            for (int r = 0; r < 64; ++r) {
                const int i = wave * 64 + r;
                const float* ar = Ab + (size_t)i * DH;
                float acc = 0.f;
                #pragma unroll
                for (int k = 0; k < 4; ++k) {
                    float4 av = *(const float4*)(ar + k * 256 + 4 * lane);
                    float4 hv = *(const float4*)(s_h + k * 256 + 4 * lane);
                    acc += av.x * hv.x + av.y * hv.y + av.z * hv.z + av.w * hv.w;
                }
                #pragma unroll
                for (int o = 32; o > 0; o >>= 1) acc += __shfl_down(acc, o, 64);
                if (lane == 0) s_add[i] = acc;
            }
            __syncthreads();
            x = s_base[tid] + s_add[tid];
        }

        // block mean/var over 1024 elements
        float s = x, sq = x * x;
        #pragma unroll
        for (int o = 32; o > 0; o >>= 1) {
            s  += __shfl_down(s,  o, 64);
            sq += __shfl_down(sq, o, 64);
        }
        if (lane == 0) { s_red[wave] = s; s_red[16 + wave] = sq; }
        __syncthreads();
        if (tid == 0) {
            float ts = 0.f, tq = 0.f;
            for (int w = 0; w < 16; ++w) { ts += s_red[w]; tq += s_red[16 + w]; }
            float mu  = ts * (1.0f / DH);
            float var = tq * (1.0f / DH) - mu * mu;
            s_red[32] = mu;
            s_red[33] = rsqrtf(var + LN_EPS);
        }
        __syncthreads();
        const float mu = s_red[32], rs = s_red[33];
        float h = (x - mu) * rs * g + bt;
        h = h > 0.f ? h : 0.f;
        s_h[tid] = h;       // safe: all s_h readers synced above
        __syncthreads();
    }

    // ---- write h_t ----
    out[(size_t)bb * DH + tid] = s_h[tid];

    // ---- A_k = LAMBDA*A + ETA*outer(h,h), coalesced float4 stream ----
    const float4* A4 = (const float4*)Ab;
    float4*       O4 = (float4*)(out + (size_t)NB * DH + ((size_t)bb << 20));
    const float4* H4 = (const float4*)s_h;
    for (int t = tid; t < DH * DH / 4; t += 1024) {
        const int i  = t >> 8;     // row (same for all lanes of a wave -> LDS broadcast)
        const int j4 = t & 255;    // float4 column index
        float4 a  = A4[t];
        float  hi = s_h[i];
        float4 hj = H4[j4];
        float4 r;
        r.x = LAMBDA * a.x + ETA * hi * hj.x;
        r.y = LAMBDA * a.y + ETA * hi * hj.y;
        r.z = LAMBDA * a.z + ETA * hi * hj.z;
        r.w = LAMBDA * a.w + ETA * hi * hj.w;
        O4[t] = r;
    }
}

extern "C" void kernel_launch(void* const* d_in, const int* in_sizes, int n_in,
                              void* d_out, int out_size, void* d_ws, size_t ws_size,
                              hipStream_t stream) {
    const float* z      = (const float*)d_in[0];
    const float* h_prev = (const float*)d_in[1];
    const float* A_prev = (const float*)d_in[2];
    const float* W_h    = (const float*)d_in[3];
    const float* W_g    = (const float*)d_in[4];
    const float* b_h    = (const float*)d_in[5];
    const float* gamma  = (const float*)d_in[6];
    const float* beta   = (const float*)d_in[7];
    float* out = (float*)d_out;

    corernn_fused<<<NB, 1024, 0, stream>>>(z, h_prev, A_prev, W_h, W_g, b_h,
                                           gamma, beta, out);
}